// Round 21
// baseline (169.794 us; speedup 1.0000x reference)
//
#include <hip/hip_runtime.h>

#define BATCH 16384
#define DIM   512
#define NCLS  2048

typedef _Float16 half8 __attribute__((ext_vector_type(8)));
typedef float    floatx16 __attribute__((ext_vector_type(16)));

__device__ inline unsigned pack2bf(float a, float b) {
    unsigned ua = (__builtin_bit_cast(unsigned, a) + 0x8000u) >> 16;
    unsigned ub = (__builtin_bit_cast(unsigned, b) + 0x8000u) >> 16;
    return ua | (ub << 16);
}
__device__ inline float ubf_lo(unsigned u) { return __builtin_bit_cast(float, u << 16); }
__device__ inline float ubf_hi(unsigned u) { return __builtin_bit_cast(float, u & 0xffff0000u); }

// ---------------- pack centers into 32x32x16 MFMA B-fragment order ----------------
// Fragment (n, s): n = 32-col block (0..63), s = 16-deep K step (0..31).
// Granule g = n*32 + s; lane l holds B[col = n*32 + (l&31)][k = s*16 + (l>>5)*8 .. +8]
// (same lane-group convention as the verified 16x16x32: low lane bits = col,
//  high lane bit selects the 8-elem k-half). One fragment = 64 lanes x 16 B = 1 KB.
__global__ __launch_bounds__(256) void pack_b3(const float* __restrict__ C,
                                               _Float16* __restrict__ BP) {
    int t = blockIdx.x * 256 + threadIdx.x;   // [0, 131072)
    int lane = t & 63, g = t >> 6;            // g in [0, 2048)
    int n = g >> 5, s = g & 31;
    int col = n * 32 + (lane & 31);
    int k   = s * 16 + (lane >> 5) * 8;
    const float4* src = reinterpret_cast<const float4*>(C + (size_t)col * DIM + k);
    float4 a = src[0], b = src[1];
    half8 h;
    h[0] = (_Float16)a.x; h[1] = (_Float16)a.y; h[2] = (_Float16)a.z; h[3] = (_Float16)a.w;
    h[4] = (_Float16)b.x; h[5] = (_Float16)b.y; h[6] = (_Float16)b.z; h[7] = (_Float16)b.w;
    *reinterpret_cast<half8*>(BP + (size_t)t * 8) = h;
}

// ---------------- 0.5 * ||c_k||^2, one wave per class ----------------
__global__ __launch_bounds__(64) void csq_kernel(const float* __restrict__ c,
                                                 float* __restrict__ hcsq) {
    int k = blockIdx.x, t = threadIdx.x;
    const float4* p = reinterpret_cast<const float4*>(c + (size_t)k * DIM);
    float s = 0.f;
    #pragma unroll
    for (int j = 0; j < 2; ++j) {
        float4 v = p[t + j * 64];
        s += v.x * v.x + v.y * v.y + v.z * v.z + v.w * v.w;
    }
    #pragma unroll
    for (int o = 32; o; o >>= 1) s += __shfl_xor(s, o);
    if (t == 0) hcsq[k] = 0.5f * s;
}

// ---------------- per-row analytic softmax base (R10-R20-verified) ----------------
__global__ __launch_bounds__(64) void rowbase_kernel(const float* __restrict__ x,
                                                     float* __restrict__ rb) {
    int b = blockIdx.x, t = threadIdx.x;
    const float4* p = reinterpret_cast<const float4*>(x + (size_t)b * DIM);
    float s = 0.f;
    #pragma unroll
    for (int j = 0; j < 2; ++j) {
        float4 v = p[t + j * 64];
        s += v.x + v.y + v.z + v.w;
    }
    #pragma unroll
    for (int o = 32; o; o >>= 1) s += __shfl_xor(s, o);
    if (t == 0) rb[b] = 0.5f * s - 85.3333333f;
}

// ---------------- fused GEMM + softmax: 32x32x16 MFMA, 2x FLOP per B-byte ----------------
// 512 blocks x 512 thr (8 waves, 128-reg tier). Block: 32 rows x all 2048 cols.
// Wave w covers ALL 32 rows x one 32-col slot per 256-col chunk (8 chunks):
// slot slR = (w + rot) & 7, chunk chR = (c0 + rot2) & 7. Per K-step: ONE 1 KB
// B-fragment load + 1 LDS af + 1 mfma_32x32x16 -> block reads B exactly once
// (1 GB L2 total, half of R13; vmem instr count also halved).
// C/D layout (HW-verified m74/m101): col = lane&31, row = (reg&3)+8*(reg>>2)+4*(lane>>5).
// Numerics (R10-R20-verified): analytic row base, clamp +-80, packed bf16 ev,
// sums re-derived from packed ev in a final pass (consistent normalization).
__global__ __launch_bounds__(512, 4) void fused_kernel(
    const float* __restrict__ X,       // [BATCH][DIM] fp32
    const _Float16* __restrict__ BP,   // packed B fragments (2 MB)
    const float* __restrict__ hcsq,    // [NCLS] 0.5*||c||^2
    const float* __restrict__ RB,      // [BATCH] row base
    float* __restrict__ O)             // [BATCH][NCLS]
{
    __shared__ __align__(16) _Float16 As2[32 * 512];  // 32 KB, fragment-packed
    __shared__ float rbL[32];                         // row bases
    __shared__ float rsum[8][32];                     // per-wave row sums

    const int tid  = threadIdx.x;
    const int lane = tid & 63;
    const int wave = tid >> 6;      // 0..7
    const int hi   = lane >> 5;     // k-half / row-group selector
    const int c31  = lane & 31;
    const int rowB = blockIdx.x * 32;
    const int chph = blockIdx.x & 7;                 // chunk rotation (decorrelation)
    const int slR  = (wave + ((blockIdx.x >> 3) & 7)) & 7;   // rotated col slot

    // ---- stage A -> As2 fragment-packed for 32x32x16 ----
    // slot t: s = t>>6, l = t&63; holds X[rowB + (l&31)][s*16 + (l>>5)*8 .. +8]
    #pragma unroll
    for (int i = 0; i < 4; ++i) {
        int t = i * 512 + tid;              // 2048 slots = 32 s x 64 lanes
        int s = t >> 6, l = t & 63;
        const float* src = X + (size_t)(rowB + (l & 31)) * DIM + s * 16 + (l >> 5) * 8;
        float4 a = *reinterpret_cast<const float4*>(src);
        float4 b = *reinterpret_cast<const float4*>(src + 4);
        half8 h;
        h[0] = (_Float16)a.x; h[1] = (_Float16)a.y; h[2] = (_Float16)a.z; h[3] = (_Float16)a.w;
        h[4] = (_Float16)b.x; h[5] = (_Float16)b.y; h[6] = (_Float16)b.z; h[7] = (_Float16)b.w;
        *reinterpret_cast<half8*>(&As2[(size_t)t * 8]) = h;
    }
    if (tid < 32) rbL[tid] = RB[rowB + tid];
    __syncthreads();

    unsigned ev[8][8];      // packed bf16 exp pairs [chunk][reg-pair] = 64 regs

    #pragma unroll
    for (int c0 = 0; c0 < 8; ++c0) {
        const int chR = (c0 + chph) & 7;        // rotated 256-col chunk
        const int n   = chR * 8 + slR;          // 32-col block index (0..63)

        floatx16 acc = {};
        const float hc = hcsq[n * 32 + c31];    // 0.5||c||^2 for this lane's col

        // fragment base: granule g = n*32 + s; addr = g*512 + lane*8 halves
        const _Float16* bb = BP + ((size_t)n * 32 * 512) + (size_t)lane * 8;

        #pragma unroll 8
        for (int s = 0; s < 32; ++s) {
            half8 bf = *reinterpret_cast<const half8*>(bb + (size_t)s * 512);
            half8 af = *reinterpret_cast<const half8*>(&As2[((size_t)s * 64 + lane) * 8]);
            acc = __builtin_amdgcn_mfma_f32_32x32x16_f16(af, bf, acc, 0, 0, 0);
        }

        // chunk epilogue: ev = bf16(exp(clamp(acc - hc - rowbase)))
        // row of reg j: (j&3) + 8*(j>>2) + 4*hi
        #pragma unroll
        for (int p = 0; p < 8; ++p) {
            const int j0 = 2 * p, j1 = 2 * p + 1;
            const int r0 = (j0 & 3) + 8 * (j0 >> 2) + 4 * hi;
            const int r1 = (j1 & 3) + 8 * (j1 >> 2) + 4 * hi;
            float z0 = acc[j0] - hc - rbL[r0];
            float z1 = acc[j1] - hc - rbL[r1];
            z0 = fminf(fmaxf(z0, -80.f), 80.f);
            z1 = fminf(fmaxf(z1, -80.f), 80.f);
            ev[c0][p] = pack2bf(__expf(z0), __expf(z1));
        }
    }

    // ---- final pass: row sums from packed ev (consistent with stored values) ----
    float tot[16];
    #pragma unroll
    for (int j = 0; j < 16; ++j) tot[j] = 0.f;
    #pragma unroll
    for (int c0 = 0; c0 < 8; ++c0)
        #pragma unroll
        for (int p = 0; p < 8; ++p) {
            unsigned u = ev[c0][p];
            tot[2 * p]     += ubf_lo(u);
            tot[2 * p + 1] += ubf_hi(u);
        }
    // butterfly over the 32-lane col group (offsets < 32 stay within group)
    #pragma unroll
    for (int off = 16; off >= 1; off >>= 1)
        #pragma unroll
        for (int j = 0; j < 16; ++j)
            tot[j] += __shfl_xor(tot[j], off);
    if (c31 == 0) {
        #pragma unroll
        for (int j = 0; j < 16; ++j)
            rsum[wave][(j & 3) + 8 * (j >> 2) + 4 * hi] = tot[j];
    }
    __syncthreads();

    float inv[16];
    #pragma unroll
    for (int j = 0; j < 16; ++j) {
        const int r = (j & 3) + 8 * (j >> 2) + 4 * hi;
        float ssum = 0.f;
        #pragma unroll
        for (int w = 0; w < 8; ++w) ssum += rsum[w][r];
        inv[j] = 1.0f / ssum;   // values >= e^-80 > 0: never 0
    }

    // ---- single write of normalized output ----
    #pragma unroll
    for (int c0 = 0; c0 < 8; ++c0) {
        const int chR = (c0 + chph) & 7;
        const int n   = chR * 8 + slR;
        const int col = n * 32 + c31;
        #pragma unroll
        for (int p = 0; p < 8; ++p) {
            unsigned u = ev[c0][p];
            const int j0 = 2 * p, j1 = 2 * p + 1;
            const int r0 = (j0 & 3) + 8 * (j0 >> 2) + 4 * hi;
            const int r1 = (j1 & 3) + 8 * (j1 >> 2) + 4 * hi;
            O[(size_t)(rowB + r0) * NCLS + col] = ubf_lo(u) * inv[j0];
            O[(size_t)(rowB + r1) * NCLS + col] = ubf_hi(u) * inv[j1];
        }
    }
}

extern "C" void kernel_launch(void* const* d_in, const int* in_sizes, int n_in,
                              void* d_out, int out_size, void* d_ws, size_t ws_size,
                              hipStream_t stream) {
    const float* x       = (const float*)d_in[0];
    const float* centers = (const float*)d_in[1];
    float* out = (float*)d_out;

    // ws: BP packed fp16 (2 MB) | 0.5*csq [NCLS] (8 KB) | rowbase [BATCH] (64 KB)
    _Float16* bp = (_Float16*)d_ws;
    float* hcsq  = (float*)(bp + (size_t)64 * 32 * 512);
    float* rb    = hcsq + NCLS;

    hipLaunchKernelGGL(pack_b3, dim3(64 * 32 * 64 / 256), dim3(256), 0, stream, centers, bp);
    hipLaunchKernelGGL(csq_kernel, dim3(NCLS), dim3(64), 0, stream, centers, hcsq);
    hipLaunchKernelGGL(rowbase_kernel, dim3(BATCH), dim3(64), 0, stream, x, rb);
    hipLaunchKernelGGL(fused_kernel, dim3(BATCH / 32), dim3(512), 0, stream,
                       x, bp, hcsq, rb, out);
}

// Round 22
// 134.991 us; speedup vs baseline: 1.2578x; 1.2578x over previous
//
#include <hip/hip_runtime.h>

#define BATCH 16384
#define DIM   512
#define NCLS  2048

typedef _Float16 half8 __attribute__((ext_vector_type(8)));
typedef float    floatx16 __attribute__((ext_vector_type(16)));

__device__ inline unsigned pack2bf(float a, float b) {
    unsigned ua = (__builtin_bit_cast(unsigned, a) + 0x8000u) >> 16;
    unsigned ub = (__builtin_bit_cast(unsigned, b) + 0x8000u) >> 16;
    return ua | (ub << 16);
}
__device__ inline float ubf_lo(unsigned u) { return __builtin_bit_cast(float, u << 16); }
__device__ inline float ubf_hi(unsigned u) { return __builtin_bit_cast(float, u & 0xffff0000u); }

// row map for 32x32x16 C/D (HW-verified m74/m101): row = (j&3) + 8*(j>>2) + 4*hi
__device__ inline int rmap(int j, int hi) { return (j & 3) + 8 * (j >> 2) + 4 * hi; }

// EW index: [b 1024][w 4][nloc 2][m 4][p 8][lane 64] (u32 = 2 rows x same col, bf16)
__device__ inline size_t ewidx(int b, int w, int nloc, int m, int p, int lane) {
    return (((((size_t)b * 4 + w) * 2 + nloc) * 4 + m) * 8 + p) * 64 + lane;
}

// ---------------- pack centers into 32x32x16 B-fragment order (R21-VERIFIED) ----------------
// Granule g = n*32 + s; lane l holds B[col = n*32 + (l&31)][k = s*16 + (l>>5)*8 .. +8]
__global__ __launch_bounds__(256) void pack_b3(const float* __restrict__ C,
                                               _Float16* __restrict__ BP) {
    int t = blockIdx.x * 256 + threadIdx.x;   // [0, 131072)
    int lane = t & 63, g = t >> 6;
    int n = g >> 5, s = g & 31;
    int col = n * 32 + (lane & 31);
    int k   = s * 16 + (lane >> 5) * 8;
    const float4* src = reinterpret_cast<const float4*>(C + (size_t)col * DIM + k);
    float4 a = src[0], b = src[1];
    half8 h;
    h[0] = (_Float16)a.x; h[1] = (_Float16)a.y; h[2] = (_Float16)a.z; h[3] = (_Float16)a.w;
    h[4] = (_Float16)b.x; h[5] = (_Float16)b.y; h[6] = (_Float16)b.z; h[7] = (_Float16)b.w;
    *reinterpret_cast<half8*>(BP + (size_t)t * 8) = h;
}

// ---------------- pack X into 32x32x16 A-fragment order (same map, 512 row-blocks) ----------------
__global__ __launch_bounds__(256) void pack_a3(const float* __restrict__ X,
                                               _Float16* __restrict__ AP) {
    int t = blockIdx.x * 256 + threadIdx.x;   // [0, 1048576)
    int lane = t & 63, g = t >> 6;            // g in [0, 16384)
    int rb_ = g >> 5, s = g & 31;             // rowblk 0..511
    int row = rb_ * 32 + (lane & 31);
    int k   = s * 16 + (lane >> 5) * 8;
    const float4* src = reinterpret_cast<const float4*>(X + (size_t)row * DIM + k);
    float4 a = src[0], b = src[1];
    half8 h;
    h[0] = (_Float16)a.x; h[1] = (_Float16)a.y; h[2] = (_Float16)a.z; h[3] = (_Float16)a.w;
    h[4] = (_Float16)b.x; h[5] = (_Float16)b.y; h[6] = (_Float16)b.z; h[7] = (_Float16)b.w;
    *reinterpret_cast<half8*>(AP + (size_t)t * 8) = h;
}

// ---------------- 0.5 * ||c_k||^2, one wave per class ----------------
__global__ __launch_bounds__(64) void csq_kernel(const float* __restrict__ c,
                                                 float* __restrict__ hcsq) {
    int k = blockIdx.x, t = threadIdx.x;
    const float4* p = reinterpret_cast<const float4*>(c + (size_t)k * DIM);
    float s = 0.f;
    #pragma unroll
    for (int j = 0; j < 2; ++j) {
        float4 v = p[t + j * 64];
        s += v.x * v.x + v.y * v.y + v.z * v.z + v.w * v.w;
    }
    #pragma unroll
    for (int o = 32; o; o >>= 1) s += __shfl_xor(s, o);
    if (t == 0) hcsq[k] = 0.5f * s;
}

// ---------------- per-row analytic softmax base (R10-R21-verified) ----------------
__global__ __launch_bounds__(64) void rowbase_kernel(const float* __restrict__ x,
                                                     float* __restrict__ rb) {
    int b = blockIdx.x, t = threadIdx.x;
    const float4* p = reinterpret_cast<const float4*>(x + (size_t)b * DIM);
    float s = 0.f;
    #pragma unroll
    for (int j = 0; j < 2; ++j) {
        float4 v = p[t + j * 64];
        s += v.x + v.y + v.z + v.w;
    }
    #pragma unroll
    for (int o = 32; o; o >>= 1) s += __shfl_xor(s, o);
    if (t == 0) rb[b] = 0.5f * s - 85.3333333f;
}

// ---------------- G: fragment-streamed GEMM + exp, zero row-state ----------------
// grid 1024 (= 128 row-tiles x 8 col-slabs), 256 thr (4 waves) -> 4 blocks/CU,
// 4 waves/SIMD (the proven sweet spot). Block: 128 rows x 256 cols.
// Wave w: nloc 0..1 -> n = csR*8 + ((w*2 + nloc + rt) & 7); m 0..3 (acc = 64 AGPR).
// A and B both stream as packed 1KB fragments from L2 (B 256 MB, A 256 MB total).
// EW=1: write packed-bf16 exp pairs to EWu. EW=0: write fp32 exp to O (fallback).
template<int EW>
__global__ __launch_bounds__(256, 4) void gemm_exp_kernel(
    const _Float16* __restrict__ AP, const _Float16* __restrict__ BP,
    const float* __restrict__ hcsq, const float* __restrict__ RBv,
    unsigned* __restrict__ EWu, float* __restrict__ O)
{
    __shared__ float rbL[128];
    const int tid  = threadIdx.x;
    const int lane = tid & 63;
    const int w    = tid >> 6;      // 0..3
    const int hi   = lane >> 5;
    const int c31  = lane & 31;
    const int b    = blockIdx.x;
    const int rt   = b >> 3;        // row-tile 0..127
    const int cs0  = b & 7;         // col-slab
    const int csR  = (cs0 + rt) & 7;    // decorrelated slab

    if (tid < 128) rbL[tid] = RBv[rt * 128 + tid];
    __syncthreads();

    #pragma unroll
    for (int nloc = 0; nloc < 2; ++nloc) {
        const int n  = csR * 8 + ((w * 2 + nloc + rt) & 7);   // 32-col block 0..63
        const float hc = hcsq[n * 32 + c31];
        const _Float16* bb = BP + (size_t)(n * 32) * 512 + (size_t)lane * 8;

        floatx16 acc[4] = {};

        #pragma unroll 8
        for (int s = 0; s < 32; ++s) {
            half8 bf = *reinterpret_cast<const half8*>(bb + (size_t)s * 512);
            #pragma unroll
            for (int m = 0; m < 4; ++m) {
                half8 af = *reinterpret_cast<const half8*>(
                    AP + (size_t)((rt * 4 + m) * 32 + s) * 512 + (size_t)lane * 8);
                acc[m] = __builtin_amdgcn_mfma_f32_32x32x16_f16(af, bf, acc[m], 0, 0, 0);
            }
        }

        #pragma unroll
        for (int m = 0; m < 4; ++m)
            #pragma unroll
            for (int p = 0; p < 8; ++p) {
                const int j0 = 2 * p, j1 = 2 * p + 1;
                const int r0 = rmap(j0, hi), r1 = rmap(j1, hi);
                float z0 = acc[m][j0] - hc - rbL[m * 32 + r0];
                float z1 = acc[m][j1] - hc - rbL[m * 32 + r1];
                z0 = fminf(fmaxf(z0, -80.f), 80.f);
                z1 = fminf(fmaxf(z1, -80.f), 80.f);
                float e0 = __expf(z0), e1 = __expf(z1);
                if (EW) {
                    EWu[ewidx(b, w, nloc, m, p, lane)] = pack2bf(e0, e1);
                } else {
                    const int col = n * 32 + c31;
                    O[(size_t)(rt * 128 + m * 32 + r0) * NCLS + col] = e0;
                    O[(size_t)(rt * 128 + m * 32 + r1) * NCLS + col] = e1;
                }
            }
    }
}

// ---------------- INV (EW path): row sums from EWu, one wave per row ----------------
__global__ __launch_bounds__(256) void inv_ew_kernel(const unsigned* __restrict__ EWu,
                                                     float* __restrict__ INV) {
    const int lane = threadIdx.x & 63;
    const int v    = threadIdx.x >> 6;
    const int r    = blockIdx.x * 4 + v;      // grid 4096
    const int rt   = r >> 7;
    const int rl   = r & 127;
    const int m    = rl >> 5;
    const int r31  = rl & 31;
    const int hi   = (r31 >> 2) & 1;
    const int j    = (r31 >> 3) * 4 + (r31 & 3);
    const int p    = j >> 1, par = j & 1;
    const int c31p = lane & 31, ch2 = lane >> 5;

    float sum = 0.f;
    #pragma unroll
    for (int i = 0; i < 32; ++i) {
        const int chunk = i * 2 + ch2;        // 0..63 = cs(8) x w(4) x nloc(2)
        const int cs = chunk >> 3, wg = (chunk >> 1) & 3, nl = chunk & 1;
        unsigned u = EWu[ewidx(rt * 8 + cs, wg, nl, m, p, hi * 32 + c31p)];
        sum += par ? ubf_hi(u) : ubf_lo(u);
    }
    #pragma unroll
    for (int off = 32; off; off >>= 1) sum += __shfl_xor(sum, off);
    if (lane == 0) INV[r] = 1.0f / sum;       // >= exp(-80) terms, never 0
}

// ---------------- N (EW path): normalized write, mirrors G's mapping ----------------
__global__ __launch_bounds__(256) void norm_ew_kernel(const unsigned* __restrict__ EWu,
                                                      const float* __restrict__ INV,
                                                      float* __restrict__ O) {
    __shared__ float invL[128];
    const int tid  = threadIdx.x;
    const int lane = tid & 63;
    const int w    = tid >> 6;
    const int hi   = lane >> 5;
    const int c31  = lane & 31;
    const int b    = blockIdx.x;
    const int rt   = b >> 3;
    const int cs0  = b & 7;
    const int csR  = (cs0 + rt) & 7;

    if (tid < 128) invL[tid] = INV[rt * 128 + tid];
    __syncthreads();

    #pragma unroll
    for (int nloc = 0; nloc < 2; ++nloc) {
        const int n   = csR * 8 + ((w * 2 + nloc + rt) & 7);  // MUST match G
        const int col = n * 32 + c31;
        #pragma unroll
        for (int m = 0; m < 4; ++m)
            #pragma unroll
            for (int p = 0; p < 8; ++p) {
                unsigned u = EWu[ewidx(b, w, nloc, m, p, lane)];
                const int r0 = rmap(2 * p, hi), r1 = rmap(2 * p + 1, hi);
                O[(size_t)(rt * 128 + m * 32 + r0) * NCLS + col] =
                    ubf_lo(u) * invL[m * 32 + r0];
                O[(size_t)(rt * 128 + m * 32 + r1) * NCLS + col] =
                    ubf_hi(u) * invL[m * 32 + r1];
            }
    }
}

// ---------------- fallback path: sums + in-place scale on fp32 O ----------------
__global__ __launch_bounds__(256) void inv_f32_kernel(const float* __restrict__ O,
                                                      float* __restrict__ INV) {
    const int lane = threadIdx.x & 63;
    const int v    = threadIdx.x >> 6;
    const int r    = blockIdx.x * 4 + v;      // grid 4096
    const float* row = O + (size_t)r * NCLS;
    float sum = 0.f;
    #pragma unroll
    for (int i = 0; i < 32; ++i) sum += row[i * 64 + lane];
    #pragma unroll
    for (int off = 32; off; off >>= 1) sum += __shfl_xor(sum, off);
    if (lane == 0) INV[r] = 1.0f / sum;
}

__global__ __launch_bounds__(256) void norm_f32_kernel(float* __restrict__ O,
                                                       const float* __restrict__ INV) {
    size_t i = ((size_t)blockIdx.x * 256 + threadIdx.x) * 4;   // grid 32768
    float4 vv = *reinterpret_cast<float4*>(O + i);
    float f = INV[i >> 11];
    vv.x *= f; vv.y *= f; vv.z *= f; vv.w *= f;
    *reinterpret_cast<float4*>(O + i) = vv;
}

extern "C" void kernel_launch(void* const* d_in, const int* in_sizes, int n_in,
                              void* d_out, int out_size, void* d_ws, size_t ws_size,
                              hipStream_t stream) {
    const float* x       = (const float*)d_in[0];
    const float* centers = (const float*)d_in[1];
    float* out = (float*)d_out;

    // ws: BP 2MB | AP 16MB | hcsq 8KB | rb 64KB | inv 64KB | [EWu 64MiB if it fits]
    _Float16* bp = (_Float16*)d_ws;
    _Float16* ap = bp + (size_t)1048576;
    float* hcsq  = (float*)(ap + (size_t)8388608);
    float* rb    = hcsq + NCLS;
    float* inv   = rb + BATCH;
    unsigned* ewu = (unsigned*)(inv + BATCH);
    const size_t need = 18874368 + (2048 + 16384 + 16384) * 4 + (size_t)16777216 * 4;
    const bool ew = (ws_size >= need);

    hipLaunchKernelGGL(pack_b3, dim3(512), dim3(256), 0, stream, centers, bp);
    hipLaunchKernelGGL(pack_a3, dim3(4096), dim3(256), 0, stream, x, ap);
    hipLaunchKernelGGL(csq_kernel, dim3(NCLS), dim3(64), 0, stream, centers, hcsq);
    hipLaunchKernelGGL(rowbase_kernel, dim3(BATCH), dim3(64), 0, stream, x, rb);

    if (ew) {
        hipLaunchKernelGGL((gemm_exp_kernel<1>), dim3(1024), dim3(256), 0, stream,
                           ap, bp, hcsq, rb, ewu, out);
        hipLaunchKernelGGL(inv_ew_kernel, dim3(4096), dim3(256), 0, stream, ewu, inv);
        hipLaunchKernelGGL(norm_ew_kernel, dim3(1024), dim3(256), 0, stream, ewu, inv, out);
    } else {
        hipLaunchKernelGGL((gemm_exp_kernel<0>), dim3(1024), dim3(256), 0, stream,
                           ap, bp, hcsq, rb, ewu, out);
        hipLaunchKernelGGL(inv_f32_kernel, dim3(4096), dim3(256), 0, stream, out, inv);
        hipLaunchKernelGGL(norm_f32_kernel, dim3(32768), dim3(256), 0, stream, out, inv);
    }
}

// Round 23
// 118.188 us; speedup vs baseline: 1.4367x; 1.1422x over previous
//
#include <hip/hip_runtime.h>

#define BATCH 16384
#define DIM   512
#define NCLS  2048

typedef _Float16 half8 __attribute__((ext_vector_type(8)));
typedef float    floatx4 __attribute__((ext_vector_type(4)));

__device__ inline unsigned pack2bf(float a, float b) {
    unsigned ua = (__builtin_bit_cast(unsigned, a) + 0x8000u) >> 16;
    unsigned ub = (__builtin_bit_cast(unsigned, b) + 0x8000u) >> 16;
    return ua | (ub << 16);
}
__device__ inline float ubf_lo(unsigned u) { return __builtin_bit_cast(float, u << 16); }
__device__ inline float ubf_hi(unsigned u) { return __builtin_bit_cast(float, u & 0xffff0000u); }

// ---------------- pack centers into bank-spread MFMA B-fragment order (R11-R20-verified) ----------------
// Granule g = (q*16 + s)*4 + ct holds C[(q*4+ct)*16 + (lane&15)][s*32 + (lane>>4)*8 .. +8]
__global__ __launch_bounds__(256) void pack_b(const float* __restrict__ C,
                                              _Float16* __restrict__ BP) {
    int t = blockIdx.x * 256 + threadIdx.x;   // [0, 131072)
    int lane = t & 63, g = t >> 6;            // g in [0, 2048)
    int ct = g & 3, s = (g >> 2) & 15, q = g >> 6;
    int col = (q * 4 + ct) * 16 + (lane & 15);
    int k   = s * 32 + (lane >> 4) * 8;
    const float4* src = reinterpret_cast<const float4*>(C + (size_t)col * DIM + k);
    float4 a = src[0], b = src[1];
    half8 h;
    h[0] = (_Float16)a.x; h[1] = (_Float16)a.y; h[2] = (_Float16)a.z; h[3] = (_Float16)a.w;
    h[4] = (_Float16)b.x; h[5] = (_Float16)b.y; h[6] = (_Float16)b.z; h[7] = (_Float16)b.w;
    *reinterpret_cast<half8*>(BP + (size_t)t * 8) = h;
}

// ---------------- 0.5 * ||c_k||^2, one wave per class ----------------
__global__ __launch_bounds__(64) void csq_kernel(const float* __restrict__ c,
                                                 float* __restrict__ hcsq) {
    int k = blockIdx.x, t = threadIdx.x;
    const float4* p = reinterpret_cast<const float4*>(c + (size_t)k * DIM);
    float s = 0.f;
    #pragma unroll
    for (int j = 0; j < 2; ++j) {
        float4 v = p[t + j * 64];
        s += v.x * v.x + v.y * v.y + v.z * v.z + v.w * v.w;
    }
    #pragma unroll
    for (int o = 32; o; o >>= 1) s += __shfl_xor(s, o);
    if (t == 0) hcsq[k] = 0.5f * s;
}

// ---------------- per-row analytic softmax base (R10-R22-verified) ----------------
__global__ __launch_bounds__(64) void rowbase_kernel(const float* __restrict__ x,
                                                     float* __restrict__ rb) {
    int b = blockIdx.x, t = threadIdx.x;
    const float4* p = reinterpret_cast<const float4*>(x + (size_t)b * DIM);
    float s = 0.f;
    #pragma unroll
    for (int j = 0; j < 2; ++j) {
        float4 v = p[t + j * 64];
        s += v.x + v.y + v.z + v.w;
    }
    #pragma unroll
    for (int o = 32; o; o >>= 1) s += __shfl_xor(s, o);
    if (t == 0) rb[b] = 0.5f * s - 85.3333333f;
}

// ---------------- fused GEMM + softmax: R13 champion + non-temporal output stores ----------------
// R23 = R13 (best verified, 106.5us) + __builtin_nontemporal_store on O writes:
// the 134 MB one-time output stream stays out of the 32-MB L2 that serves the
// 2 GB of BP reads (R13 sits exactly on the ~19 TB/s L2-service wall; reducing
// BP eviction is the only zero-register lever left).
__global__ __launch_bounds__(1024, 4) void fused_kernel(
    const float* __restrict__ X,       // [BATCH][DIM] fp32
    const _Float16* __restrict__ BP,   // packed B fragments (2 MB)
    const float* __restrict__ hcsq,    // [NCLS] 0.5*||c||^2
    const float* __restrict__ RB,      // [BATCH] row base
    float* __restrict__ O)             // [BATCH][NCLS]
{
    __shared__ __align__(16) _Float16 As[32 * 512];   // 32 KB, granule-swizzled
    __shared__ float rsum[16][32];

    const int tid  = threadIdx.x;
    const int lane = tid & 63;
    const int wave = tid >> 6;      // 0..15
    const int rt   = wave & 1;      // 16-row half
    const int cw   = wave >> 1;     // col group 0..7
    const int l4   = lane >> 4;     // 16-lane group 0..3
    const int r15  = lane & 15;
    const int rowB = blockIdx.x * 32;
    const int cq   = (cw + blockIdx.x) & 7;            // rotated quad (R13-verified)
    const int chph = (blockIdx.x >> 3) & 3;            // chunk phase

    // ---- stage A: fp32 -> fp16, 16B granules XOR-swizzled (slot = g ^ (row&7)) ----
    #pragma unroll
    for (int i = 0; i < 2; ++i) {
        int G = i * 1024 + tid;             // 2048 granules = 32 rows x 64
        int row = G >> 6, g = G & 63;
        const float* src = X + (size_t)(rowB + row) * DIM + g * 8;
        float4 a = *reinterpret_cast<const float4*>(src);
        float4 b = *reinterpret_cast<const float4*>(src + 4);
        half8 h;
        h[0] = (_Float16)a.x; h[1] = (_Float16)a.y; h[2] = (_Float16)a.z; h[3] = (_Float16)a.w;
        h[4] = (_Float16)b.x; h[5] = (_Float16)b.y; h[6] = (_Float16)b.z; h[7] = (_Float16)b.w;
        *reinterpret_cast<half8*>(&As[(row * 64 + (g ^ (row & 7))) * 8]) = h;
    }
    __syncthreads();

    // per-thread row bases (rows: rowB + rt*16 + l4*4 + j)
    float rbv[4];
    #pragma unroll
    for (int j = 0; j < 4; ++j)
        rbv[j] = RB[rowB + rt * 16 + l4 * 4 + j];

    unsigned ev[4][4][2];   // packed bf16 exp pairs [c0][ct][jpair] = 32 regs
    float tot[4] = {0.f, 0.f, 0.f, 0.f};

    #pragma unroll
    for (int c0 = 0; c0 < 4; ++c0) {
        const int chR = (c0 + chph) & 3;    // rotated chunk

        floatx4 acc[4];
        #pragma unroll
        for (int ct = 0; ct < 4; ++ct)
            acc[ct] = (floatx4){0.f, 0.f, 0.f, 0.f};

        float hc[4];
        #pragma unroll
        for (int ct = 0; ct < 4; ++ct)
            hc[ct] = hcsq[chR * 512 + cq * 64 + ct * 16 + r15];

        // quad q = chR*8 + cq; granule base = q*64; per (s,ct): + s*4 + ct
        const _Float16* bb = BP + ((size_t)(chR * 8 + cq) * 64 * 64 + lane) * 8;

        #pragma unroll 4
        for (int s = 0; s < 16; ++s) {
            half8 bf[4];
            #pragma unroll
            for (int ct = 0; ct < 4; ++ct)
                bf[ct] = *reinterpret_cast<const half8*>(
                    bb + (size_t)((s * 4 + ct) * 64) * 8);
            const int kg = s * 4 + l4;          // A k-granule
            const int sw = kg ^ (r15 & 7);
            half8 af = *reinterpret_cast<const half8*>(
                &As[((rt * 16 + r15) * 64 + sw) * 8]);
            #pragma unroll
            for (int ct = 0; ct < 4; ++ct)
                acc[ct] = __builtin_amdgcn_mfma_f32_16x16x32_f16(af, bf[ct], acc[ct], 0, 0, 0);
        }

        // chunk epilogue: ev = bf16(exp(clamp(l - base))); accumulate fp32 sums
        #pragma unroll
        for (int ct = 0; ct < 4; ++ct)
            #pragma unroll
            for (int pp = 0; pp < 2; ++pp) {
                float z0 = acc[ct][2 * pp]     - hc[ct] - rbv[2 * pp];
                float z1 = acc[ct][2 * pp + 1] - hc[ct] - rbv[2 * pp + 1];
                z0 = fminf(fmaxf(z0, -80.f), 80.f);
                z1 = fminf(fmaxf(z1, -80.f), 80.f);
                unsigned u = pack2bf(__expf(z0), __expf(z1));
                ev[c0][ct][pp] = u;
                tot[2 * pp]     += ubf_lo(u);
                tot[2 * pp + 1] += ubf_hi(u);
            }
    }

    // ---- row sums: butterfly within 16-lane group + cross-wave LDS ----
    #pragma unroll
    for (int off = 8; off >= 1; off >>= 1)
        #pragma unroll
        for (int j = 0; j < 4; ++j)
            tot[j] += __shfl_xor(tot[j], off);
    if (r15 == 0) {
        #pragma unroll
        for (int j = 0; j < 4; ++j)
            rsum[wave][rt * 16 + l4 * 4 + j] = tot[j];
    }
    __syncthreads();

    float inv[4];
    #pragma unroll
    for (int j = 0; j < 4; ++j) {
        const int r = rt * 16 + l4 * 4 + j;
        float ssum = 0.f;
        #pragma unroll
        for (int c = 0; c < 8; ++c) ssum += rsum[c * 2 + rt][r];
        inv[j] = 1.0f / ssum;   // values >= e^-80 > 0: never 0
    }

    // ---- single write of normalized output (C/D: col=r15, row=l4*4+j) ----
    // non-temporal: one-time stream, keep it out of L2 (BP must stay resident)
    #pragma unroll
    for (int c0 = 0; c0 < 4; ++c0) {
        const int chR = (c0 + chph) & 3;
        #pragma unroll
        for (int ct = 0; ct < 4; ++ct) {
            const int col = chR * 512 + cq * 64 + ct * 16 + r15;
            float* op = O + (size_t)(rowB + rt * 16 + l4 * 4) * NCLS + col;
            #pragma unroll
            for (int pp = 0; pp < 2; ++pp) {
                unsigned u = ev[c0][ct][pp];
                __builtin_nontemporal_store(ubf_lo(u) * inv[2 * pp],
                                            &op[(size_t)(2 * pp) * NCLS]);
                __builtin_nontemporal_store(ubf_hi(u) * inv[2 * pp + 1],
                                            &op[(size_t)(2 * pp + 1) * NCLS]);
            }
        }
    }
}

extern "C" void kernel_launch(void* const* d_in, const int* in_sizes, int n_in,
                              void* d_out, int out_size, void* d_ws, size_t ws_size,
                              hipStream_t stream) {
    const float* x       = (const float*)d_in[0];
    const float* centers = (const float*)d_in[1];
    float* out = (float*)d_out;

    // ws: BP packed fp16 (2 MB) | 0.5*csq [NCLS] (8 KB) | rowbase [BATCH] (64 KB)
    _Float16* bp = (_Float16*)d_ws;
    float* hcsq  = (float*)(bp + (size_t)128 * 16 * 64 * 8);
    float* rb    = hcsq + NCLS;

    hipLaunchKernelGGL(pack_b, dim3(128 * 16 * 64 / 256), dim3(256), 0, stream, centers, bp);
    hipLaunchKernelGGL(csq_kernel, dim3(NCLS), dim3(64), 0, stream, centers, hcsq);
    hipLaunchKernelGGL(rowbase_kernel, dim3(BATCH), dim3(64), 0, stream, x, rb);
    hipLaunchKernelGGL(fused_kernel, dim3(BATCH / 32), dim3(1024), 0, stream,
                       x, bp, hcsq, rb, out);
}